// Round 18
// baseline (871.245 us; speedup 1.0000x reference)
//
#include <hip/hip_runtime.h>
#include <hip/hip_bf16.h>

// MoE: T=2048, H=2048, I=5632, E=8, top-2 renormalized.
// cvt x bf16 (scratch=d_out) -> fused route+lists(+inv) -> GEMM1 (x@w1^T SwiGLU -> bf16 h)
// -> GEMM2 (h@w2^T -> gbuf rows, non-atomic) -> combine (out[t]=w0*g[r0]+w1*g[r1]).
// R18 = R17 + BK 32->64 (half the barriers, double work/barrier). Tests the last
// untried axis: fixed per-barrier overhead (R16 proved memory latency is NOT the
// stall: counted vmcnt was exactly neutral). LDS 96KB -> 1 block/CU (R13: neutral).
// A layout becomes [row][8 slot16], read slot (kk*4+ks)^(r&7), glds src pre-swizzled.
// B: reg roundtrip, 16 regs, 2 ds_writes at phys (2*bu2+j)^(br&7) (2-way free).

#define TT 2048
#define HH 2048
#define II 5632
#define NE 8

using f32x4  = __attribute__((ext_vector_type(4))) float;
using bf16x8 = __attribute__((ext_vector_type(8))) short;

__device__ __forceinline__ uint32_t bfbits(float f) {
    __hip_bfloat16 h = __float2bfloat16(f);
    unsigned short u;
    __builtin_memcpy(&u, &h, 2);
    return (uint32_t)u;
}
__device__ __forceinline__ uint32_t pk2(float a, float b) {
    return bfbits(a) | (bfbits(b) << 16);
}
__device__ __forceinline__ uint4 pk8(const float4& a, const float4& b) {
    uint4 r;
    r.x = pk2(a.x, a.y); r.y = pk2(a.z, a.w);
    r.z = pk2(b.x, b.y); r.w = pk2(b.z, b.w);
    return r;
}
__device__ __forceinline__ void gl16(const void* g, void* l) {
    __builtin_amdgcn_global_load_lds(
        (const __attribute__((address_space(1))) unsigned int*)g,
        (__attribute__((address_space(3))) unsigned int*)l, 16, 0, 0);
}

// ---------------- x -> bf16 ----------------
__global__ void cvt_x(const float* __restrict__ x, __hip_bfloat16* __restrict__ xb) {
    const int i = (blockIdx.x * 256 + threadIdx.x) * 8;
    float4 a = *(const float4*)(x + i);
    float4 b = *(const float4*)(x + i + 4);
    *(uint4*)(xb + i) = pk8(a, b);
}

// ---------------- fused routing + per-expert list build ----------------
__global__ void route_build(const float* __restrict__ gating,
                            int* __restrict__ list_tok, int* __restrict__ inv,
                            float* __restrict__ tk_w, int* __restrict__ counts) {
    const int e = blockIdx.x;
    const int tid = threadIdx.x;
    int flag[8]; float wt[8];
    int cnt = 0;
#pragma unroll
    for (int j = 0; j < 8; j++) {
        int t = tid * 8 + j;
        float g[NE];
#pragma unroll
        for (int k = 0; k < NE; k++) g[k] = gating[t * NE + k];
        int i0 = 0; float b0 = g[0];
#pragma unroll
        for (int k = 1; k < NE; k++) if (g[k] > b0) { b0 = g[k]; i0 = k; }
        int i1 = (i0 == 0) ? 1 : 0; float b1 = g[i1];
#pragma unroll
        for (int k = 0; k < NE; k++) if (k != i0 && g[k] > b1) { b1 = g[k]; i1 = k; }
        float ex = __expf(b1 - b0);
        int f = -1; float wv = 0.f;
        if (i0 == e) { f = 0; wv = 1.f / (1.f + ex); }
        else if (i1 == e) { f = 1; wv = ex / (1.f + ex); }
        flag[j] = f; wt[j] = wv;
        cnt += (f >= 0) ? 1 : 0;
    }
    __shared__ int s[256];
    s[tid] = cnt;
    __syncthreads();
    for (int d = 1; d < 256; d <<= 1) {
        int v = (tid >= d) ? s[tid - d] : 0;
        __syncthreads();
        s[tid] += v;
        __syncthreads();
    }
    int pos = s[tid] - cnt;
#pragma unroll
    for (int j = 0; j < 8; j++) {
        if (flag[j] >= 0) {
            int t = tid * 8 + j;
            list_tok[e * TT + pos] = t;
            inv[2 * t + flag[j]] = e * TT + pos;
            tk_w[2 * t + flag[j]] = wt[j];
            pos++;
        }
    }
    if (tid == 255) counts[e] = s[255];
}

// ---------------- GEMM1: tile 256(M) x 64 I-cols, BK=64, 512 thr / 8 waves ----------------
// LDS: A [256 rows][8 slot16] 32KB x2 + B [128 wrows][8 slot16] 16KB x2 = 96KB (1 blk/CU).
__global__ __launch_bounds__(512, 2) void gemm1_swiglu(
    const __hip_bfloat16* __restrict__ xb, const float* __restrict__ w1,
    const int* __restrict__ list_tok, const int* __restrict__ counts,
    __hip_bfloat16* __restrict__ hbuf) {
    const int e = blockIdx.y >> 3;
    const int mt = blockIdx.y & 7;
    const int cnt = counts[e];
    const int row0 = mt * 256;
    if (row0 >= cnt) return;
    int off = 0;
#pragma unroll
    for (int i = 0; i < NE; i++) if (i < e) off += counts[i];
    const int valid = min(256, cnt - row0);
    const int n0 = blockIdx.x * 64;
    const int tid = threadIdx.x;
    const int w = tid >> 6, l = tid & 63;   // 8 waves

    __shared__ uint4 As[2 * 2048];  // [buf][row][phys slot]; phys p holds logical p^(r&7)
    __shared__ uint4 Bs[2][1024];   // [buf][wrow][phys slot] (g 0..63, u 64..127)

    // A staging: call c covers rows (w*4+c)*8 + (l>>3); lane phys slot = l&7
    const char* aSrc[4];
#pragma unroll
    for (int c = 0; c < 4; c++) {
        int rc = (w * 4 + c) * 8 + (l >> 3);
        int tok = list_tok[e * TT + row0 + min(rc, valid - 1)];
        int lg = (l & 7) ^ (l >> 3);          // logical slot for this phys position
        aSrc[c] = (const char*)(xb + (size_t)tok * HH + lg * 8);
    }
    auto STAGEA = [&](int kt, int b) {
        char* ab = (char*)As + b * 32768 + w * 4096;
#pragma unroll
        for (int c = 0; c < 4; c++) gl16(aSrc[c] + (size_t)kt * 128, ab + c * 1024);
    };

    // B staging: thread -> wrow br (0..127), covers f32 cols [bu2*16, bu2*16+16)
    const int br = tid >> 2, bu2 = tid & 3;
    const float* bSrc;
    {
        const float* base = w1 + (size_t)e * (2 * II) * HH;
        int r = (br < 64) ? (n0 + br) : (II + n0 + (br - 64));
        bSrc = base + (size_t)r * HH + bu2 * 16;
    }
    const int bp0 = br * 8 + ((2 * bu2) ^ (br & 7));
    const int bp1 = br * 8 + ((2 * bu2 + 1) ^ (br & 7));

    float4 rB0, rB1, rB2, rB3;
    auto LOADB = [&](int kt) {
        const int k = kt * 64;
        rB0 = *(const float4*)(bSrc + k);      rB1 = *(const float4*)(bSrc + k + 4);
        rB2 = *(const float4*)(bSrc + k + 8);  rB3 = *(const float4*)(bSrc + k + 12);
    };
    auto STOREB = [&](int b) {
        Bs[b][bp0] = pk8(rB0, rB1);
        Bs[b][bp1] = pk8(rB2, rB3);
    };

    // wave grid 4M x 2N; wave tile 64 rows x 32 cols
    const int wm = w >> 1, wn = w & 1;
    const int l15 = l & 15, ks = l >> 4;
    int aidx[4][2], bgidx[2][2], buidx[2][2];
#pragma unroll
    for (int m = 0; m < 4; m++) {
        int r = wm * 64 + m * 16 + l15;
#pragma unroll
        for (int kk = 0; kk < 2; kk++) aidx[m][kk] = r * 8 + ((kk * 4 + ks) ^ (r & 7));
    }
#pragma unroll
    for (int n = 0; n < 2; n++) {
        int cg = wn * 32 + n * 16 + l15;
        int cu = cg + 64;
#pragma unroll
        for (int kk = 0; kk < 2; kk++) {
            bgidx[n][kk] = cg * 8 + ((kk * 4 + ks) ^ (cg & 7));
            buidx[n][kk] = cu * 8 + ((kk * 4 + ks) ^ (cu & 7));
        }
    }

    f32x4 accg[4][2], accu[4][2];
#pragma unroll
    for (int m = 0; m < 4; m++)
#pragma unroll
        for (int n = 0; n < 2; n++) { accg[m][n] = 0; accu[m][n] = 0; }

    STAGEA(0, 0); LOADB(0); STOREB(0);
    __syncthreads();
    const int KT = HH / 64;  // 32
    for (int kt = 0; kt < KT; ++kt) {
        const int cur = kt & 1;
        if (kt + 1 < KT) {
            STAGEA(kt + 1, cur ^ 1);
            LOADB(kt + 1);
        }
        const uint4* Ab = As + cur * 2048;
#pragma unroll
        for (int kk = 0; kk < 2; kk++) {
            bf16x8 gf[2], uf[2];
#pragma unroll
            for (int n = 0; n < 2; n++) {
                uint4 t = Bs[cur][bgidx[n][kk]]; gf[n] = __builtin_bit_cast(bf16x8, t);
                uint4 t2 = Bs[cur][buidx[n][kk]]; uf[n] = __builtin_bit_cast(bf16x8, t2);
            }
#pragma unroll
            for (int m = 0; m < 4; m++) {
                uint4 t = Ab[aidx[m][kk]];
                bf16x8 af = __builtin_bit_cast(bf16x8, t);
#pragma unroll
                for (int n = 0; n < 2; n++) {
                    accg[m][n] = __builtin_amdgcn_mfma_f32_16x16x32_bf16(af, gf[n], accg[m][n], 0, 0, 0);
                    accu[m][n] = __builtin_amdgcn_mfma_f32_16x16x32_bf16(af, uf[n], accu[m][n], 0, 0, 0);
                }
            }
        }
        if (kt + 1 < KT) STOREB(cur ^ 1);
        __syncthreads();
    }

    // epilogue: h = silu(g)*u -> bf16
#pragma unroll
    for (int m = 0; m < 4; m++) {
#pragma unroll
        for (int r = 0; r < 4; r++) {
            const int lr = wm * 64 + m * 16 + ks * 4 + r;
            if (lr < valid) {
                __hip_bfloat16* hrow = hbuf + (size_t)(off + row0 + lr) * II;
#pragma unroll
                for (int n = 0; n < 2; n++) {
                    const int col = n0 + wn * 32 + n * 16 + l15;
                    float g = accg[m][n][r], u = accu[m][n][r];
                    float h = g / (1.f + __expf(-g)) * u;
                    hrow[col] = __float2bfloat16(h);
                }
            }
        }
    }
}

// ---------------- GEMM2: tile 256(M) x 128(N), BK=64, 512 thr / 8 waves, NON-ATOMIC ----------------
// LDS: A 32KB x2 + B [128 N-rows][8 slot16] 16KB x2 = 96KB.
__global__ __launch_bounds__(512, 2) void gemm2_rows(
    const __hip_bfloat16* __restrict__ hbuf, const float* __restrict__ w2,
    const int* __restrict__ counts, float* __restrict__ gbuf) {
    const int e = blockIdx.y >> 3;
    const int mt = blockIdx.y & 7;
    const int cnt = counts[e];
    const int row0 = mt * 256;
    if (row0 >= cnt) return;
    int off = 0;
#pragma unroll
    for (int i = 0; i < NE; i++) if (i < e) off += counts[i];
    const int valid = min(256, cnt - row0);
    const int n0 = blockIdx.x * 128;
    const int tid = threadIdx.x;
    const int w = tid >> 6, l = tid & 63;

    __shared__ uint4 As[2 * 2048];
    __shared__ uint4 Bs[2][1024];

    const char* aSrc[4];
#pragma unroll
    for (int c = 0; c < 4; c++) {
        int rc = (w * 4 + c) * 8 + (l >> 3);
        int lg = (l & 7) ^ (l >> 3);
        aSrc[c] = (const char*)(hbuf + (size_t)(off + row0 + min(rc, valid - 1)) * II + lg * 8);
    }
    auto STAGEA = [&](int kt, int b) {
        char* ab = (char*)As + b * 32768 + w * 4096;
#pragma unroll
        for (int c = 0; c < 4; c++) gl16(aSrc[c] + (size_t)kt * 128, ab + c * 1024);
    };

    const int br = tid >> 2, bu2 = tid & 3;
    const float* bSrc = w2 + (size_t)e * HH * II + (size_t)(n0 + br) * II + bu2 * 16;
    const int bp0 = br * 8 + ((2 * bu2) ^ (br & 7));
    const int bp1 = br * 8 + ((2 * bu2 + 1) ^ (br & 7));

    float4 rB0, rB1, rB2, rB3;
    auto LOADB = [&](int kt) {
        const int k = kt * 64;
        rB0 = *(const float4*)(bSrc + k);      rB1 = *(const float4*)(bSrc + k + 4);
        rB2 = *(const float4*)(bSrc + k + 8);  rB3 = *(const float4*)(bSrc + k + 12);
    };
    auto STOREB = [&](int b) {
        Bs[b][bp0] = pk8(rB0, rB1);
        Bs[b][bp1] = pk8(rB2, rB3);
    };

    // wave grid 2M x 4N; wave tile 128 rows x 32 cols
    const int wm = w >> 2, wn = w & 3;
    const int l15 = l & 15, ks = l >> 4;
    int aidx[8][2], bidx[2][2];
#pragma unroll
    for (int m = 0; m < 8; m++) {
        int r = wm * 128 + m * 16 + l15;
#pragma unroll
        for (int kk = 0; kk < 2; kk++) aidx[m][kk] = r * 8 + ((kk * 4 + ks) ^ (r & 7));
    }
#pragma unroll
    for (int n = 0; n < 2; n++) {
        int c = wn * 32 + n * 16 + l15;
#pragma unroll
        for (int kk = 0; kk < 2; kk++) bidx[n][kk] = c * 8 + ((kk * 4 + ks) ^ (c & 7));
    }

    f32x4 acc[8][2];
#pragma unroll
    for (int m = 0; m < 8; m++)
#pragma unroll
        for (int n = 0; n < 2; n++) acc[m][n] = 0;

    STAGEA(0, 0); LOADB(0); STOREB(0);
    __syncthreads();
    const int KT = II / 64;  // 88
    for (int kt = 0; kt < KT; ++kt) {
        const int cur = kt & 1;
        if (kt + 1 < KT) {
            STAGEA(kt + 1, cur ^ 1);
            LOADB(kt + 1);
        }
        const uint4* Ab = As + cur * 2048;
#pragma unroll
        for (int kk = 0; kk < 2; kk++) {
            bf16x8 bf[2];
#pragma unroll
            for (int n = 0; n < 2; n++) { uint4 t = Bs[cur][bidx[n][kk]]; bf[n] = __builtin_bit_cast(bf16x8, t); }
#pragma unroll
            for (int m = 0; m < 8; m++) {
                uint4 t = Ab[aidx[m][kk]];
                bf16x8 af = __builtin_bit_cast(bf16x8, t);
#pragma unroll
                for (int n = 0; n < 2; n++)
                    acc[m][n] = __builtin_amdgcn_mfma_f32_16x16x32_bf16(af, bf[n], acc[m][n], 0, 0, 0);
            }
        }
        if (kt + 1 < KT) STOREB(cur ^ 1);
        __syncthreads();
    }

    // epilogue: plain coalesced stores
#pragma unroll
    for (int m = 0; m < 8; m++) {
#pragma unroll
        for (int r = 0; r < 4; r++) {
            const int lr = wm * 128 + m * 16 + ks * 4 + r;
            if (lr < valid) {
                float* orow = gbuf + (size_t)(off + row0 + lr) * HH;
#pragma unroll
                for (int n = 0; n < 2; n++) {
                    const int col = n0 + wn * 32 + n * 16 + l15;
                    orow[col] = acc[m][n][r];
                }
            }
        }
    }
}

// ---------------- combine: out[t] = w0*gbuf[row(t,0)] + w1*gbuf[row(t,1)] ----------------
__global__ void combine(const float* __restrict__ gbuf, const int* __restrict__ inv,
                        const float* __restrict__ tk_w, const int* __restrict__ counts,
                        float* __restrict__ out) {
    const int idx = blockIdx.x * 256 + threadIdx.x;
    const int t = idx >> 8;
    const int c = (idx & 255) * 8;
    int offs[NE];
    {
        int s = 0;
#pragma unroll
        for (int e = 0; e < NE; e++) { offs[e] = s; s += counts[e]; }
    }
    const int i0 = inv[2 * t], i1 = inv[2 * t + 1];
    const float w0 = tk_w[2 * t], w1 = tk_w[2 * t + 1];
    const float* g0 = gbuf + (size_t)(offs[i0 >> 11] + (i0 & 2047)) * HH + c;
    const float* g1 = gbuf + (size_t)(offs[i1 >> 11] + (i1 & 2047)) * HH + c;
    float4 a0 = *(const float4*)(g0);
    float4 a1 = *(const float4*)(g0 + 4);
    float4 b0 = *(const float4*)(g1);
    float4 b1 = *(const float4*)(g1 + 4);
    float4 o0, o1;
    o0.x = w0 * a0.x + w1 * b0.x; o0.y = w0 * a0.y + w1 * b0.y;
    o0.z = w0 * a0.z + w1 * b0.z; o0.w = w0 * a0.w + w1 * b0.w;
    o1.x = w0 * a1.x + w1 * b1.x; o1.y = w0 * a1.y + w1 * b1.y;
    o1.z = w0 * a1.z + w1 * b1.z; o1.w = w0 * a1.w + w1 * b1.w;
    float* op = out + (size_t)t * HH + c;
    *(float4*)(op) = o0;
    *(float4*)(op + 4) = o1;
}

extern "C" void kernel_launch(void* const* d_in, const int* in_sizes, int n_in,
                              void* d_out, int out_size, void* d_ws, size_t ws_size,
                              hipStream_t stream) {
    const float* x      = (const float*)d_in[0];
    const float* gating = (const float*)d_in[1];
    const float* w1     = (const float*)d_in[2];
    const float* w2     = (const float*)d_in[3];
    float* out = (float*)d_out;
    char* ws = (char*)d_ws;

    int*   list_tok = (int*)(ws + 0);              // 64 KB
    int*   inv      = (int*)(ws + (64 << 10));     // 16 KB
    int*   counts   = (int*)(ws + (96 << 10));     // 32 B
    float* tk_w     = (float*)(ws + (116 << 10));  // 16 KB
    __hip_bfloat16* hbuf = (__hip_bfloat16*)(ws + (1 << 20));        // 46.1 MB
    float* gbuf = (float*)(ws + (size_t)(64 << 20));                 // 33.5 MB

    // xb (bf16 x, 8.4 MB) lives in d_out until gemm1 is done; combine overwrites out fully.
    __hip_bfloat16* xb = (__hip_bfloat16*)d_out;

    cvt_x<<<TT * HH / (256 * 8), 256, 0, stream>>>(x, xb);
    route_build<<<NE, 256, 0, stream>>>(gating, list_tok, inv, tk_w, counts);
    gemm1_swiglu<<<dim3(II / 64, NE * 8), 512, 0, stream>>>(xb, w1, list_tok, counts, hbuf);
    gemm2_rows<<<dim3(HH / 128, NE * 8), 512, 0, stream>>>(hbuf, w2, counts, gbuf);
    combine<<<TT * HH / (256 * 8), 256, 0, stream>>>(gbuf, inv, tk_w, counts, out);
}

// Round 19
// 672.940 us; speedup vs baseline: 1.2947x; 1.2947x over previous
//
#include <hip/hip_runtime.h>
#include <hip/hip_bf16.h>

// MoE: T=2048, H=2048, I=5632, E=8, top-2 renormalized.
// cvt x bf16 (scratch=d_out) -> fused route+lists(+inv) -> GEMM1 (x@w1^T SwiGLU -> bf16 h)
// -> GEMM2 (h@w2^T -> gbuf rows, non-atomic) -> combine (out[t]=w0*g[r0]+w1*g[r1]).
// R19 = R17 restored (session best: 672.8us). R18's BK=64 regressed (-30%): 1 blk/CU
// lost more than halved barriers gained. Final model: gemm phase is service-rate-bound
// (~65K concurrent B-row streams pull ~2 TB/s HBM vs 6.7 contiguous); AGPR budget
// (64/wave) boxes tile area/traffic. Measured-null levers: 9 schedules, 3 occupancies,
// 2 XCD remaps (negative), 4 tile shapes, 3 staging modes, BK=64 (negative).
// Wins: bf16 staging, 256-tall tiles (R11), non-atomic combine (R15), fused routing (R17).

#define TT 2048
#define HH 2048
#define II 5632
#define NE 8

using f32x4  = __attribute__((ext_vector_type(4))) float;
using bf16x8 = __attribute__((ext_vector_type(8))) short;

__device__ __forceinline__ uint32_t bfbits(float f) {
    __hip_bfloat16 h = __float2bfloat16(f);
    unsigned short u;
    __builtin_memcpy(&u, &h, 2);
    return (uint32_t)u;
}
__device__ __forceinline__ uint32_t pk2(float a, float b) {
    return bfbits(a) | (bfbits(b) << 16);
}
__device__ __forceinline__ uint4 pk8(const float4& a, const float4& b) {
    uint4 r;
    r.x = pk2(a.x, a.y); r.y = pk2(a.z, a.w);
    r.z = pk2(b.x, b.y); r.w = pk2(b.z, b.w);
    return r;
}
__device__ __forceinline__ void gl16(const void* g, void* l) {
    __builtin_amdgcn_global_load_lds(
        (const __attribute__((address_space(1))) unsigned int*)g,
        (__attribute__((address_space(3))) unsigned int*)l, 16, 0, 0);
}

// ---------------- x -> bf16 ----------------
__global__ void cvt_x(const float* __restrict__ x, __hip_bfloat16* __restrict__ xb) {
    const int i = (blockIdx.x * 256 + threadIdx.x) * 8;
    float4 a = *(const float4*)(x + i);
    float4 b = *(const float4*)(x + i + 4);
    *(uint4*)(xb + i) = pk8(a, b);
}

// ---------------- fused routing + per-expert list build ----------------
// 8 blocks (one per expert). Each block re-computes top-2 routing for all 2048 tokens
// (redundant, 64KB reads) and compacts its own token list. Each token's 2 weight slots
// are written by exactly the two owning expert blocks -> tk_w fully populated.
__global__ void route_build(const float* __restrict__ gating,
                            int* __restrict__ list_tok, int* __restrict__ inv,
                            float* __restrict__ tk_w, int* __restrict__ counts) {
    const int e = blockIdx.x;
    const int tid = threadIdx.x;
    int flag[8]; float wt[8];
    int cnt = 0;
#pragma unroll
    for (int j = 0; j < 8; j++) {
        int t = tid * 8 + j;
        float g[NE];
#pragma unroll
        for (int k = 0; k < NE; k++) g[k] = gating[t * NE + k];
        int i0 = 0; float b0 = g[0];
#pragma unroll
        for (int k = 1; k < NE; k++) if (g[k] > b0) { b0 = g[k]; i0 = k; }
        int i1 = (i0 == 0) ? 1 : 0; float b1 = g[i1];
#pragma unroll
        for (int k = 0; k < NE; k++) if (k != i0 && g[k] > b1) { b1 = g[k]; i1 = k; }
        float ex = __expf(b1 - b0);
        int f = -1; float wv = 0.f;
        if (i0 == e) { f = 0; wv = 1.f / (1.f + ex); }
        else if (i1 == e) { f = 1; wv = ex / (1.f + ex); }
        flag[j] = f; wt[j] = wv;
        cnt += (f >= 0) ? 1 : 0;
    }
    __shared__ int s[256];
    s[tid] = cnt;
    __syncthreads();
    for (int d = 1; d < 256; d <<= 1) {
        int v = (tid >= d) ? s[tid - d] : 0;
        __syncthreads();
        s[tid] += v;
        __syncthreads();
    }
    int pos = s[tid] - cnt;
#pragma unroll
    for (int j = 0; j < 8; j++) {
        if (flag[j] >= 0) {
            int t = tid * 8 + j;
            list_tok[e * TT + pos] = t;
            inv[2 * t + flag[j]] = e * TT + pos;
            tk_w[2 * t + flag[j]] = wt[j];
            pos++;
        }
    }
    if (tid == 255) counts[e] = s[255];
}

// ---------------- GEMM1: tile 256(M) x 64 I-cols, BK=32, 512 thr / 8 waves ----------------
// Wave grid 4Mx2N, wave tile 64x32cols, dual acc = 16 frags = 64 AGPR.
// LDS: A 16KB x2 (glds) + B(g+u 128 rows) 8KB x2 = 48KB.
__global__ __launch_bounds__(512, 4) void gemm1_swiglu(
    const __hip_bfloat16* __restrict__ xb, const float* __restrict__ w1,
    const int* __restrict__ list_tok, const int* __restrict__ counts,
    __hip_bfloat16* __restrict__ hbuf) {
    const int e = blockIdx.y >> 3;
    const int mt = blockIdx.y & 7;
    const int cnt = counts[e];
    const int row0 = mt * 256;
    if (row0 >= cnt) return;
    int off = 0;
#pragma unroll
    for (int i = 0; i < NE; i++) if (i < e) off += counts[i];
    const int valid = min(256, cnt - row0);
    const int n0 = blockIdx.x * 64;
    const int tid = threadIdx.x;
    const int w = tid >> 6, l = tid & 63;   // 8 waves

    __shared__ uint4 As[2 * 1024];  // [buf][row 0..255][slot 0..3] linear; src pre-swizzled
    __shared__ uint4 Bs[2][512];    // [buf][row 0..127][slot] (g rows 0..63, u rows 64..127)

    // A staging: call c covers rows c*128 + w*16 + (l>>2)
    const char *aSrc0, *aSrc1;
    {
        int r0 = w * 16 + (l >> 2);
        int r1 = r0 + 128;
        int t0 = list_tok[e * TT + row0 + min(r0, valid - 1)];
        int t1 = list_tok[e * TT + row0 + min(r1, valid - 1)];
        int s0 = (l & 3) ^ ((r0 >> 1) & 3);
        int s1 = (l & 3) ^ ((r1 >> 1) & 3);
        aSrc0 = (const char*)(xb + (size_t)t0 * HH + s0 * 8);
        aSrc1 = (const char*)(xb + (size_t)t1 * HH + s1 * 8);
    }
    auto STAGEA = [&](int kt, int b) {
        char* ab = (char*)As + b * 16384 + w * 1024;
        gl16(aSrc0 + (size_t)kt * 64, ab);
        gl16(aSrc1 + (size_t)kt * 64, ab + 8192);
    };

    // B staging: thread -> row br (0..127), slot bu2 (0..3); br<64 -> g, else u
    const int br = tid >> 2, bu2 = tid & 3;
    const float* bSrc;
    {
        const float* base = w1 + (size_t)e * (2 * II) * HH;
        int r = (br < 64) ? (n0 + br) : (II + n0 + (br - 64));
        bSrc = base + (size_t)r * HH + bu2 * 8;
    }
    const int bwi = br * 4 + (bu2 ^ ((br >> 1) & 3));

    float4 rBa, rBb;
    auto LOADB = [&](int kt) {
        const int k = kt * 32;
        rBa = *(const float4*)(bSrc + k); rBb = *(const float4*)(bSrc + k + 4);
    };
    auto STOREB = [&](int b) { Bs[b][bwi] = pk8(rBa, rBb); };

    // wave grid 4M x 2N; wave tile 64 rows x 32 cols
    const int wm = w >> 1, wn = w & 1;
    const int l15 = l & 15, ks = l >> 4;
    int aidx[4], bgidx[2], buidx[2];
#pragma unroll
    for (int m = 0; m < 4; m++) { int r = wm * 64 + m * 16 + l15; aidx[m] = r * 4 + (ks ^ ((r >> 1) & 3)); }
#pragma unroll
    for (int n = 0; n < 2; n++) {
        int cg = wn * 32 + n * 16 + l15;       // g row in Bs
        int cu = cg + 64;                       // u row in Bs
        bgidx[n] = cg * 4 + (ks ^ ((cg >> 1) & 3));
        buidx[n] = cu * 4 + (ks ^ ((cu >> 1) & 3));
    }

    f32x4 accg[4][2], accu[4][2];
#pragma unroll
    for (int m = 0; m < 4; m++)
#pragma unroll
        for (int n = 0; n < 2; n++) { accg[m][n] = 0; accu[m][n] = 0; }

    STAGEA(0, 0); LOADB(0); STOREB(0);
    __syncthreads();
    const int KT = HH / 32;  // 64
#pragma unroll 2
    for (int kt = 0; kt < KT; ++kt) {
        const int cur = kt & 1;
        if (kt + 1 < KT) {
            STAGEA(kt + 1, cur ^ 1);
            LOADB(kt + 1);
        }
        bf16x8 gf[2], uf[2];
#pragma unroll
        for (int n = 0; n < 2; n++) {
            uint4 t = Bs[cur][bgidx[n]]; gf[n] = __builtin_bit_cast(bf16x8, t);
            uint4 t2 = Bs[cur][buidx[n]]; uf[n] = __builtin_bit_cast(bf16x8, t2);
        }
        const uint4* Ab = As + cur * 1024;
#pragma unroll
        for (int m = 0; m < 4; m++) {
            uint4 t = Ab[aidx[m]];
            bf16x8 af = __builtin_bit_cast(bf16x8, t);
#pragma unroll
            for (int n = 0; n < 2; n++) {
                accg[m][n] = __builtin_amdgcn_mfma_f32_16x16x32_bf16(af, gf[n], accg[m][n], 0, 0, 0);
                accu[m][n] = __builtin_amdgcn_mfma_f32_16x16x32_bf16(af, uf[n], accu[m][n], 0, 0, 0);
            }
        }
        if (kt + 1 < KT) STOREB(cur ^ 1);
        __syncthreads();
    }

    // epilogue: h = silu(g)*u -> bf16
#pragma unroll
    for (int m = 0; m < 4; m++) {
#pragma unroll
        for (int r = 0; r < 4; r++) {
            const int lr = wm * 64 + m * 16 + ks * 4 + r;
            if (lr < valid) {
                __hip_bfloat16* hrow = hbuf + (size_t)(off + row0 + lr) * II;
#pragma unroll
                for (int n = 0; n < 2; n++) {
                    const int col = n0 + wn * 32 + n * 16 + l15;
                    float g = accg[m][n][r], u = accu[m][n][r];
                    float h = g / (1.f + __expf(-g)) * u;
                    hrow[col] = __float2bfloat16(h);
                }
            }
        }
    }
}

// ---------------- GEMM2: tile 256(M) x 128(N), BK=32, 512 thr / 8 waves, NON-ATOMIC ----------------
// Wave grid 2Mx4N, wave tile 128x32, acc[8][2] = 16 frags = 64 AGPR.
__global__ __launch_bounds__(512, 4) void gemm2_rows(
    const __hip_bfloat16* __restrict__ hbuf, const float* __restrict__ w2,
    const int* __restrict__ counts, float* __restrict__ gbuf) {
    const int e = blockIdx.y >> 3;
    const int mt = blockIdx.y & 7;
    const int cnt = counts[e];
    const int row0 = mt * 256;
    if (row0 >= cnt) return;
    int off = 0;
#pragma unroll
    for (int i = 0; i < NE; i++) if (i < e) off += counts[i];
    const int valid = min(256, cnt - row0);
    const int n0 = blockIdx.x * 128;
    const int tid = threadIdx.x;
    const int w = tid >> 6, l = tid & 63;

    __shared__ uint4 As[2 * 1024];  // 256 rows x 4 slots per buf
    __shared__ uint4 Bs[2][512];    // 128 rows x 4 slots per buf

    const char *aSrc0, *aSrc1;
    {
        int r0 = w * 16 + (l >> 2);
        int r1 = r0 + 128;
        int s0 = (l & 3) ^ ((r0 >> 1) & 3);
        int s1 = (l & 3) ^ ((r1 >> 1) & 3);
        aSrc0 = (const char*)(hbuf + (size_t)(off + row0 + min(r0, valid - 1)) * II + s0 * 8);
        aSrc1 = (const char*)(hbuf + (size_t)(off + row0 + min(r1, valid - 1)) * II + s1 * 8);
    }
    auto STAGEA = [&](int kt, int b) {
        char* ab = (char*)As + b * 16384 + w * 1024;
        gl16(aSrc0 + (size_t)kt * 64, ab);
        gl16(aSrc1 + (size_t)kt * 64, ab + 8192);
    };

    const int br = tid >> 2, bu2 = tid & 3;
    const float* bSrc = w2 + (size_t)e * HH * II + (size_t)(n0 + br) * II + bu2 * 8;
    const int bwi = br * 4 + (bu2 ^ ((br >> 1) & 3));

    float4 rBa, rBb;
    auto LOADB = [&](int kt) {
        const int k = kt * 32;
        rBa = *(const float4*)(bSrc + k); rBb = *(const float4*)(bSrc + k + 4);
    };
    auto STOREB = [&](int b) { Bs[b][bwi] = pk8(rBa, rBb); };

    // wave grid 2M x 4N; wave tile 128 rows x 32 cols
    const int wm = w >> 2, wn = w & 3;
    const int l15 = l & 15, ks = l >> 4;
    int aidx[8], bidx[2];
#pragma unroll
    for (int m = 0; m < 8; m++) { int r = wm * 128 + m * 16 + l15; aidx[m] = r * 4 + (ks ^ ((r >> 1) & 3)); }
#pragma unroll
    for (int n = 0; n < 2; n++) { int c = wn * 32 + n * 16 + l15; bidx[n] = c * 4 + (ks ^ ((c >> 1) & 3)); }

    f32x4 acc[8][2];
#pragma unroll
    for (int m = 0; m < 8; m++)
#pragma unroll
        for (int n = 0; n < 2; n++) acc[m][n] = 0;

    STAGEA(0, 0); LOADB(0); STOREB(0);
    __syncthreads();
    const int KT = II / 32;  // 176
#pragma unroll 2
    for (int kt = 0; kt < KT; ++kt) {
        const int cur = kt & 1;
        if (kt + 1 < KT) {
            STAGEA(kt + 1, cur ^ 1);
            LOADB(kt + 1);
        }
        bf16x8 bf[2];
#pragma unroll
        for (int n = 0; n < 2; n++) { uint4 t = Bs[cur][bidx[n]]; bf[n] = __builtin_bit_cast(bf16x8, t); }
        const uint4* Ab = As + cur * 1024;
#pragma unroll
        for (int m = 0; m < 8; m++) {
            uint4 t = Ab[aidx[m]];
            bf16x8 af = __builtin_bit_cast(bf16x8, t);
#pragma unroll
            for (int n = 0; n < 2; n++)
                acc[m][n] = __builtin_amdgcn_mfma_f32_16x16x32_bf16(af, bf[n], acc[m][n], 0, 0, 0);
        }
        if (kt + 1 < KT) STOREB(cur ^ 1);
        __syncthreads();
    }

    // epilogue: plain coalesced stores (each live row owned by exactly one block)
#pragma unroll
    for (int m = 0; m < 8; m++) {
#pragma unroll
        for (int r = 0; r < 4; r++) {
            const int lr = wm * 128 + m * 16 + ks * 4 + r;
            if (lr < valid) {
                float* orow = gbuf + (size_t)(off + row0 + lr) * HH;
#pragma unroll
                for (int n = 0; n < 2; n++) {
                    const int col = n0 + wn * 32 + n * 16 + l15;
                    orow[col] = acc[m][n][r];
                }
            }
        }
    }
}

// ---------------- combine: out[t] = w0*gbuf[row(t,0)] + w1*gbuf[row(t,1)] ----------------
__global__ void combine(const float* __restrict__ gbuf, const int* __restrict__ inv,
                        const float* __restrict__ tk_w, const int* __restrict__ counts,
                        float* __restrict__ out) {
    const int idx = blockIdx.x * 256 + threadIdx.x;
    const int t = idx >> 8;
    const int c = (idx & 255) * 8;
    int offs[NE];
    {
        int s = 0;
#pragma unroll
        for (int e = 0; e < NE; e++) { offs[e] = s; s += counts[e]; }
    }
    const int i0 = inv[2 * t], i1 = inv[2 * t + 1];
    const float w0 = tk_w[2 * t], w1 = tk_w[2 * t + 1];
    const float* g0 = gbuf + (size_t)(offs[i0 >> 11] + (i0 & 2047)) * HH + c;
    const float* g1 = gbuf + (size_t)(offs[i1 >> 11] + (i1 & 2047)) * HH + c;
    float4 a0 = *(const float4*)(g0);
    float4 a1 = *(const float4*)(g0 + 4);
    float4 b0 = *(const float4*)(g1);
    float4 b1 = *(const float4*)(g1 + 4);
    float4 o0, o1;
    o0.x = w0 * a0.x + w1 * b0.x; o0.y = w0 * a0.y + w1 * b0.y;
    o0.z = w0 * a0.z + w1 * b0.z; o0.w = w0 * a0.w + w1 * b0.w;
    o1.x = w0 * a1.x + w1 * b1.x; o1.y = w0 * a1.y + w1 * b1.y;
    o1.z = w0 * a1.z + w1 * b1.z; o1.w = w0 * a1.w + w1 * b1.w;
    float* op = out + (size_t)t * HH + c;
    *(float4*)(op) = o0;
    *(float4*)(op + 4) = o1;
}

extern "C" void kernel_launch(void* const* d_in, const int* in_sizes, int n_in,
                              void* d_out, int out_size, void* d_ws, size_t ws_size,
                              hipStream_t stream) {
    const float* x      = (const float*)d_in[0];
    const float* gating = (const float*)d_in[1];
    const float* w1     = (const float*)d_in[2];
    const float* w2     = (const float*)d_in[3];
    float* out = (float*)d_out;
    char* ws = (char*)d_ws;

    int*   list_tok = (int*)(ws + 0);              // 64 KB
    int*   inv      = (int*)(ws + (64 << 10));     // 16 KB
    int*   counts   = (int*)(ws + (96 << 10));     // 32 B
    float* tk_w     = (float*)(ws + (116 << 10));  // 16 KB
    __hip_bfloat16* hbuf = (__hip_bfloat16*)(ws + (1 << 20));        // 46.1 MB
    float* gbuf = (float*)(ws + (size_t)(64 << 20));                 // 33.5 MB

    // xb (bf16 x, 8.4 MB) lives in d_out until gemm1 is done; combine overwrites out fully.
    __hip_bfloat16* xb = (__hip_bfloat16*)d_out;

    cvt_x<<<TT * HH / (256 * 8), 256, 0, stream>>>(x, xb);
    route_build<<<NE, 256, 0, stream>>>(gating, list_tok, inv, tk_w, counts);
    gemm1_swiglu<<<dim3(II / 64, NE * 8), 512, 0, stream>>>(xb, w1, list_tok, counts, hbuf);
    gemm2_rows<<<dim3(HH / 128, NE * 8), 512, 0, stream>>>(hbuf, w2, counts, gbuf);
    combine<<<TT * HH / (256 * 8), 256, 0, stream>>>(gbuf, inv, tk_w, counts, out);
}